// Round 4
// baseline (210.509 us; speedup 1.0000x reference)
//
#include <hip/hip_runtime.h>
#include <math.h>

#define BATCH 128
#define SEQ   2048
#define HID   1024
#define CDIM  256
#define SPLIT 16
#define ROWS_PER (SEQ / SPLIT)   // 128
#define KC1   16                 // mlp1 k-chunks (each 64)

typedef float vf4 __attribute__((ext_vector_type(4)));
typedef int   vi4 __attribute__((ext_vector_type(4)));

// ---------------------------------------------------------------------------
// Kernel 1: partial masked sums over a chunk of the sequence + mask counts.
// grid (BATCH, SPLIT), block 256. Thread t owns float4 at h = t*4 (256*4=HID).
// Non-temporal: features are streamed exactly once (1 GiB > L3).
// Every thread redundantly accumulates the chunk's mask sum (broadcast loads);
// thread 0 writes it. Block (0,0) also zeroes the sim_loss ticket counter.
// ---------------------------------------------------------------------------
__global__ __launch_bounds__(256) void pool_partial_kernel(
    const float* __restrict__ feat, const int* __restrict__ mask,
    float* __restrict__ partial, int* __restrict__ cntp,
    unsigned* __restrict__ counter)
{
    const int b     = blockIdx.x;
    const int chunk = blockIdx.y;
    const int t     = threadIdx.x;

    const vf4* fp = reinterpret_cast<const vf4*>(feat) +
                    ((size_t)b * SEQ + (size_t)chunk * ROWS_PER) * (HID / 4);
    const vi4* mp = reinterpret_cast<const vi4*>(
                        mask + (size_t)b * SEQ + (size_t)chunk * ROWS_PER);

    vf4 acc = {0.f, 0.f, 0.f, 0.f};
    int csum = 0;
    for (int s = 0; s < ROWS_PER; s += 8) {
        const vi4 m0 = mp[s / 4];
        const vi4 m1 = mp[s / 4 + 1];
        csum += m0.x + m0.y + m0.z + m0.w + m1.x + m1.y + m1.z + m1.w;
        float mm[8];
        mm[0] = (float)m0.x; mm[1] = (float)m0.y; mm[2] = (float)m0.z; mm[3] = (float)m0.w;
        mm[4] = (float)m1.x; mm[5] = (float)m1.y; mm[6] = (float)m1.z; mm[7] = (float)m1.w;
        #pragma unroll
        for (int u = 0; u < 8; ++u) {
            const vf4 v = __builtin_nontemporal_load(&fp[(size_t)(s + u) * (HID / 4) + t]);
            acc += v * mm[u];
        }
    }
    reinterpret_cast<vf4*>(partial)[((size_t)b * SPLIT + chunk) * (HID / 4) + t] = acc;
    if (t == 0) {
        cntp[b * SPLIT + chunk] = csum;
        if (b == 0 && chunk == 0) *counter = 0u;
    }
}

// ---------------------------------------------------------------------------
// Kernel 2: fused {pool finalize for an 8x64 slice} + mlp1 split-K GEMM.
// W1 is [H,H] (in,out) row-major. grid (4 jc, 16 bg, 16 kc), block 256.
// part1[kc][b][j].
// ---------------------------------------------------------------------------
__global__ __launch_bounds__(256) void mlp1_fused_kernel(
    const float* __restrict__ partial, const int* __restrict__ cntp,
    const float* __restrict__ W1, float* __restrict__ part1)
{
    const int jc = blockIdx.x;
    const int bg = blockIdx.y;
    const int kc = blockIdx.z;
    const int t  = threadIdx.x;

    __shared__ float ps[8][64];   // pooled slice, 2 KiB
    __shared__ float invs[8];

    if (t < 8) {
        const int* cp = cntp + (size_t)(bg * 8 + t) * SPLIT;
        int c = 0;
        #pragma unroll
        for (int p = 0; p < SPLIT; ++p) c += cp[p];
        invs[t] = 1.0f / (float)c;
    }

    const int r  = t >> 4;    // 0..7  (valid for t<128)
    const int c4 = t & 15;    // 0..15
    vf4 acc4 = {0.f, 0.f, 0.f, 0.f};
    if (t < 128) {
        const vf4* pp = reinterpret_cast<const vf4*>(partial);
        #pragma unroll
        for (int p = 0; p < SPLIT; ++p)
            acc4 += pp[((size_t)(bg * 8 + r) * SPLIT + p) * (HID / 4) + kc * 16 + c4];
    }
    __syncthreads();
    if (t < 128)
        *reinterpret_cast<vf4*>(&ps[r][c4 * 4]) = acc4 * invs[r];
    __syncthreads();

    const int j = jc * 256 + t;
    const float* w = W1 + (size_t)(kc * 64) * HID + j;

    float acc[8];
    #pragma unroll
    for (int rr = 0; rr < 8; ++rr) acc[rr] = 0.f;

    #pragma unroll
    for (int k = 0; k < 64; k += 8) {
        float wv[8];
        #pragma unroll
        for (int u = 0; u < 8; ++u) wv[u] = w[(size_t)(k + u) * HID];
        #pragma unroll
        for (int u = 0; u < 8; ++u) {
            #pragma unroll
            for (int rr = 0; rr < 8; ++rr)
                acc[rr] = fmaf(ps[rr][k + u], wv[u], acc[rr]);
        }
    }
    #pragma unroll
    for (int rr = 0; rr < 8; ++rr)
        part1[((size_t)kc * BATCH + bg * 8 + rr) * HID + j] = acc[rr];
}

// ---------------------------------------------------------------------------
// Kernel 3: full mlp2 per batch row: reduce part1 + bias + relu (staged in
// LDS), 4-way k-split GEMM in-block, combine, bias, L2-normalize -> d_out.
// grid BATCH, block 1024 (j = t&255, kc = t>>8).
// ---------------------------------------------------------------------------
__global__ __launch_bounds__(1024) void mlp2_full_kernel(
    const float* __restrict__ part1, const float* __restrict__ b1,
    const float* __restrict__ W2, const float* __restrict__ b2,
    float* __restrict__ proj)
{
    const int b  = blockIdx.x;
    const int t  = threadIdx.x;
    const int j  = t & 255;
    const int kc = t >> 8;

    __shared__ float hs[HID];          // 4 KiB
    __shared__ float pacc[4][CDIM];    // 4 KiB
    __shared__ float red[CDIM];        // 1 KiB

    float s = b1[t];
    #pragma unroll
    for (int p = 0; p < KC1; ++p)
        s += part1[((size_t)p * BATCH + b) * HID + t];
    hs[t] = fmaxf(s, 0.f);
    __syncthreads();

    const float* w = W2 + (size_t)(kc * 256) * CDIM + j;
    const float* h = hs + kc * 256;
    float acc = 0.f;
    #pragma unroll
    for (int k = 0; k < 256; k += 8) {
        float wv[8];
        #pragma unroll
        for (int u = 0; u < 8; ++u) wv[u] = w[(size_t)(k + u) * CDIM];
        #pragma unroll
        for (int u = 0; u < 8; ++u) acc = fmaf(h[k + u], wv[u], acc);
    }
    pacc[kc][j] = acc;
    __syncthreads();

    float tot = 0.f;
    if (t < CDIM) {
        tot = b2[t] + pacc[0][t] + pacc[1][t] + pacc[2][t] + pacc[3][t];
        red[t] = tot * tot;
    }
    __syncthreads();
    for (int off = CDIM / 2; off > 0; off >>= 1) {
        if (t < off) red[t] += red[t + off];
        __syncthreads();
    }
    if (t < CDIM) {
        const float norm = fmaxf(sqrtf(red[0]), 1e-12f);
        proj[(size_t)b * CDIM + t] = tot / norm;
    }
}

// ---------------------------------------------------------------------------
// Kernel 4: fused sim row + per-row loss + last-block mean (ticket pattern).
// grid BATCH, block BATCH. Deterministic: reduced values & order are fixed.
// ---------------------------------------------------------------------------
__global__ __launch_bounds__(128) void sim_loss_kernel(
    const float* __restrict__ proj, const float* __restrict__ temp,
    const int* __restrict__ lang, float* __restrict__ loss_part,
    unsigned* __restrict__ counter, float* __restrict__ out_loss)
{
    const int i = blockIdx.x;
    const int j = threadIdx.x;

    __shared__ float pi[CDIM];
    if (j < CDIM / 4)
        reinterpret_cast<vf4*>(pi)[j] =
            reinterpret_cast<const vf4*>(proj + (size_t)i * CDIM)[j];
    __syncthreads();

    const vf4* pj = reinterpret_cast<const vf4*>(proj + (size_t)j * CDIM);
    float acc = 0.f;
    #pragma unroll 8
    for (int c = 0; c < CDIM / 4; ++c) {
        const vf4 v = pj[c];
        acc = fmaf(pi[4 * c + 0], v.x, acc);
        acc = fmaf(pi[4 * c + 1], v.y, acc);
        acc = fmaf(pi[4 * c + 2], v.z, acc);
        acc = fmaf(pi[4 * c + 3], v.w, acc);
    }
    const float s = acc / temp[0];
    const int li = lang[i];

    __shared__ float r1[BATCH];
    __shared__ int   ci[BATCH];

    r1[j] = s;
    __syncthreads();
    for (int off = BATCH / 2; off > 0; off >>= 1) {
        if (j < off) r1[j] = fmaxf(r1[j], r1[j + off]);
        __syncthreads();
    }
    const float m = r1[0];
    __syncthreads();

    r1[j] = expf(s - m);
    __syncthreads();
    for (int off = BATCH / 2; off > 0; off >>= 1) {
        if (j < off) r1[j] += r1[j + off];
        __syncthreads();
    }
    const float lse = m + logf(r1[0]);
    __syncthreads();

    const bool sel = (lang[j] != li) && (j != i);
    r1[j] = sel ? s : 0.f;
    ci[j] = sel ? 1 : 0;
    __syncthreads();
    for (int off = BATCH / 2; off > 0; off >>= 1) {
        if (j < off) { r1[j] += r1[j + off]; ci[j] += ci[j + off]; }
        __syncthreads();
    }

    __shared__ bool last;
    if (j == 0) {
        loss_part[i] = (float)ci[0] * lse - r1[0];
        __threadfence();                       // release loss_part[i]
        const unsigned old = atomicAdd(counter, 1u);   // device scope
        last = (old == BATCH - 1);
    }
    __syncthreads();
    if (last) {                                // block-uniform branch
        __threadfence();                       // acquire others' loss_part
        r1[j] = loss_part[j];
        __syncthreads();
        for (int off = BATCH / 2; off > 0; off >>= 1) {
            if (j < off) r1[j] += r1[j + off];
            __syncthreads();
        }
        if (j == 0) out_loss[0] = r1[0] / (float)BATCH;
    }
}

// ---------------------------------------------------------------------------
extern "C" void kernel_launch(void* const* d_in, const int* in_sizes, int n_in,
                              void* d_out, int out_size, void* d_ws, size_t ws_size,
                              hipStream_t stream)
{
    const float* feat = (const float*)d_in[0];
    const float* W1   = (const float*)d_in[1];
    const float* b1   = (const float*)d_in[2];
    const float* W2   = (const float*)d_in[3];
    const float* b2   = (const float*)d_in[4];
    const float* temp = (const float*)d_in[5];
    const int*   lang = (const int*)d_in[6];
    const int*   amask= (const int*)d_in[7];
    float* out = (float*)d_out;
    float* ws  = (float*)d_ws;

    float*    partial   = ws;                                      // B*SPLIT*H (8 MiB)
    float*    part1     = partial + (size_t)BATCH * SPLIT * HID;   // KC1*B*H   (8 MiB)
    float*    loss_part = part1 + (size_t)KC1 * BATCH * HID;       // B
    int*      cntp      = (int*)(loss_part + BATCH);               // B*SPLIT
    unsigned* counter   = (unsigned*)(cntp + BATCH * SPLIT);       // 1

    pool_partial_kernel<<<dim3(BATCH, SPLIT), 256, 0, stream>>>(
        feat, amask, partial, cntp, counter);
    mlp1_fused_kernel<<<dim3(HID / 256, BATCH / 8, KC1), 256, 0, stream>>>(
        partial, cntp, W1, part1);
    mlp2_full_kernel<<<BATCH, 1024, 0, stream>>>(part1, b1, W2, b2, out);
    sim_loss_kernel<<<BATCH, BATCH, 0, stream>>>(
        out, temp, lang, loss_part, counter, out + (size_t)BATCH * CDIM);
}